// Round 1
// baseline (75.411 us; speedup 1.0000x reference)
//
#include <hip/hip_runtime.h>
#include <stdint.h>
#include <math.h>

#define NB 8
#define NN 128
#define NC 64
#define DEG 10
#define NUM_STEPS 5

// ---------------------------------------------------------------------------
// Kernel 1: neighbor-list extraction.
// Edges for global node g live at dst[g*DEG .. g*DEG+9]; local id = dst & 127.
// Reference does dense_adj -> top_k(DEG): distinct neighbors sorted ascending,
// deg = count of distinct. Bitmask (2x u64) + ctz walk reproduces that exactly.
// ---------------------------------------------------------------------------
__global__ __launch_bounds__(256) void build_nbrs(
    const int* __restrict__ dst_s, const int* __restrict__ dst_t,
    int* __restrict__ nbr_s, int* __restrict__ deg_s,
    int* __restrict__ nbr_t, int* __restrict__ deg_t)
{
    int g = blockIdx.x * 256 + threadIdx.x;   // grid is exactly 2*NB*NN threads
    const int* dst; int* nbr; int* deg; int node;
    if (g < NB * NN) { node = g;           dst = dst_s; nbr = nbr_s; deg = deg_s; }
    else             { node = g - NB * NN; dst = dst_t; nbr = nbr_t; deg = deg_t; }

    unsigned long long mlo = 0ull, mhi = 0ull;
    #pragma unroll
    for (int k = 0; k < DEG; ++k) {
        int d = dst[node * DEG + k] & (NN - 1);
        if (d < 64) mlo |= 1ull << d;
        else        mhi |= 1ull << (d - 64);
    }
    int cnt = 0;
    while (mlo) { int t = __builtin_ctzll(mlo); mlo &= (mlo - 1ull); nbr[node * DEG + cnt] = t;      ++cnt; }
    while (mhi) { int t = __builtin_ctzll(mhi); mhi &= (mhi - 1ull); nbr[node * DEG + cnt] = 64 + t; ++cnt; }
    deg[node] = cnt;
    for (int p = cnt; p < DEG; ++p) nbr[node * DEG + p] = 0;  // masked slots, never used
}

// ---------------------------------------------------------------------------
// Kernel 2: sim[b,i,j] = dot(x_s[b,i,:], x_t[b,j,:]).  Block = (b,i), thread=j.
// x_s row loads are wave-uniform (broadcast); x_t rows hit L1/L2 on reuse.
// ---------------------------------------------------------------------------
__global__ __launch_bounds__(128) void sim_kernel(
    const float* __restrict__ xs, const float* __restrict__ xt,
    float* __restrict__ sim)
{
    int bi = blockIdx.x;
    int b = bi >> 7, i = bi & 127, j = threadIdx.x;
    const float4* a  = (const float4*)(xs + (size_t)(b * NN + i) * NC);
    const float4* bt = (const float4*)(xt + (size_t)(b * NN + j) * NC);
    float acc = 0.f;
    #pragma unroll
    for (int k = 0; k < NC / 4; ++k) {
        float4 av = a[k], bv = bt[k];
        acc += av.x * bv.x + av.y * bv.y + av.z * bv.z + av.w * bv.w;
    }
    sim[(size_t)(b * NN + i) * NN + j] = acc;
}

// ---------------------------------------------------------------------------
// Kernel 3: per (b,i) block, thread j: build 10x10 S_hat from staged sim rows,
// masked row-softmax, /tau, 5 Sinkhorn iters (exact IEEE divs, reference op
// order), argmax rows (strict > keeps first occurrence like jnp.argmax),
// cost = sum of chosen S_hat, sim2 = sim + cost/(1+M), block softmax over j.
// Masked entries are EXACT zeros throughout (matches softmax(NEG)->0, where->0).
// ---------------------------------------------------------------------------
__global__ __launch_bounds__(128) void main_kernel(
    const float* __restrict__ sim,
    const int* __restrict__ nbr_s, const int* __restrict__ deg_s,
    const int* __restrict__ nbr_t, const int* __restrict__ deg_t,
    float* __restrict__ out)
{
    __shared__ float srow[DEG][NN];   // sim rows of i's neighbors
    __shared__ float smax[2], ssum[2];

    int bi = blockIdx.x;
    int b = bi >> 7, i = bi & 127, j = threadIdx.x;
    int gs = b * NN + i, gt = b * NN + j;

    int dsi = deg_s[gs];              // uniform across block
    int nsp[DEG];
    #pragma unroll
    for (int p = 0; p < DEG; ++p) nsp[p] = nbr_s[gs * DEG + p];

    // stage neighbor sim rows (coalesced, 128 floats per row)
    #pragma unroll
    for (int p = 0; p < DEG; ++p) {
        if (p < dsi) srow[p][j] = sim[(size_t)(b * NN + nsp[p]) * NN + j];
    }
    __syncthreads();

    int dtj = deg_t[gt];
    int ntq[DEG];
    #pragma unroll
    for (int q = 0; q < DEG; ++q) ntq[q] = nbr_t[gt * DEG + q];

    // Gather S_hat (masked -> 0)
    float S[DEG][DEG];
    #pragma unroll
    for (int p = 0; p < DEG; ++p) {
        bool pv = (p < dsi);
        #pragma unroll
        for (int q = 0; q < DEG; ++q) {
            bool qv = (q < dtj);
            S[p][q] = (pv && qv) ? srow[p][ntq[q]] : 0.0f;
        }
    }

    // masked row softmax, then /tau (both exact divisions, reference order)
    #pragma unroll
    for (int p = 0; p < DEG; ++p) {
        if (p < dsi) {                       // uniform branch
            float mx = -INFINITY;
            #pragma unroll
            for (int q = 0; q < DEG; ++q) if (q < dtj) mx = fmaxf(mx, S[p][q]);
            float sum = 0.f;
            #pragma unroll
            for (int q = 0; q < DEG; ++q) {
                float e = (q < dtj) ? expf(S[p][q] - mx) : 0.0f;
                S[p][q] = e;
                sum += e;
            }
            #pragma unroll
            for (int q = 0; q < DEG; ++q) {
                float v = S[p][q] / sum;     // softmax normalize (exact div)
                v = v / 0.1f;                // / tau (exact div)
                S[p][q] = (q < dtj) ? v : 0.0f;
            }
        }
        // p >= dsi rows: already all-zero
    }

    // 5 Sinkhorn iterations: column then row normalization, +1e-8 after sum
    #pragma unroll 1
    for (int it = 0; it < NUM_STEPS; ++it) {
        #pragma unroll
        for (int q = 0; q < DEG; ++q) {
            float cs = S[0][q];
            #pragma unroll
            for (int p = 1; p < DEG; ++p) cs += S[p][q];
            cs += 1e-8f;
            #pragma unroll
            for (int p = 0; p < DEG; ++p) S[p][q] = S[p][q] / cs;
        }
        #pragma unroll
        for (int p = 0; p < DEG; ++p) {
            float rs = S[p][0];
            #pragma unroll
            for (int q = 1; q < DEG; ++q) rs += S[p][q];
            rs += 1e-8f;
            #pragma unroll
            for (int q = 0; q < DEG; ++q) S[p][q] = S[p][q] / rs;
        }
    }

    // argmax per row (first max), gather original S_hat from LDS, sum
    float cost = 0.f;
    #pragma unroll
    for (int p = 0; p < DEG; ++p) {
        if (p < dsi) {                       // uniform branch
            float best = S[p][0];
            int   bc   = ntq[0];
            bool  bval = (0 < dtj);
            #pragma unroll
            for (int q = 1; q < DEG; ++q) {
                if (S[p][q] > best) { best = S[p][q]; bc = ntq[q]; bval = (q < dtj); }
            }
            if (bval) cost += srow[p][bc];
        }
    }

    float M = (float)((dsi > dtj) ? dsi : dtj);
    float v = sim[(size_t)gs * NN + j] + cost / (1.0f + M);

    // block softmax over j (128 threads = 2 waves)
    float wm = v;
    #pragma unroll
    for (int off = 32; off; off >>= 1) wm = fmaxf(wm, __shfl_xor(wm, off));
    int wid = threadIdx.x >> 6;
    if ((threadIdx.x & 63) == 0) smax[wid] = wm;
    __syncthreads();
    float bm = fmaxf(smax[0], smax[1]);
    float e = expf(v - bm);
    float wsum = e;
    #pragma unroll
    for (int off = 32; off; off >>= 1) wsum += __shfl_xor(wsum, off);
    if ((threadIdx.x & 63) == 0) ssum[wid] = wsum;
    __syncthreads();
    float bs = ssum[0] + ssum[1];

    out[(size_t)gs * NN + j] = e / bs;
}

// ---------------------------------------------------------------------------
extern "C" void kernel_launch(void* const* d_in, const int* in_sizes, int n_in,
                              void* d_out, int out_size, void* d_ws, size_t ws_size,
                              hipStream_t stream) {
    (void)in_sizes; (void)n_in; (void)out_size; (void)ws_size;
    const float* x_s  = (const float*)d_in[0];
    const int*   ei_s = (const int*)  d_in[1];
    const float* x_t  = (const float*)d_in[3];
    const int*   ei_t = (const int*)  d_in[4];
    float* out = (float*)d_out;

    char* ws = (char*)d_ws;
    float* sim   = (float*)ws;                          // 8*128*128*4 = 524288 B
    int*   nbr_s = (int*)(ws + 524288);                 // 1024*10*4   = 40960 B
    int*   deg_s = (int*)(ws + 524288 + 40960);         // 1024*4      = 4096 B
    int*   nbr_t = (int*)(ws + 524288 + 45056);         // 40960 B
    int*   deg_t = (int*)(ws + 524288 + 86016);         // 4096 B

    const int* dst_s = ei_s + NB * NN * DEG;            // second row of edge_index
    const int* dst_t = ei_t + NB * NN * DEG;

    hipLaunchKernelGGL(build_nbrs, dim3(8), dim3(256), 0, stream,
                       dst_s, dst_t, nbr_s, deg_s, nbr_t, deg_t);
    hipLaunchKernelGGL(sim_kernel, dim3(NB * NN), dim3(NN), 0, stream,
                       x_s, x_t, sim);
    hipLaunchKernelGGL(main_kernel, dim3(NB * NN), dim3(NN), 0, stream,
                       sim, nbr_s, deg_s, nbr_t, deg_t, out);
}

// Round 2
// 36.914 us; speedup vs baseline: 2.0428x; 2.0428x over previous
//
#include <hip/hip_runtime.h>
#include <stdint.h>
#include <math.h>

#define NB 8
#define NN 128
#define NC 64
#define DEG 10
#define NUM_STEPS 5

// ---------------------------------------------------------------------------
// Kernel 1: neighbor-list extraction (distinct neighbors sorted ascending,
// matching to_dense_adj -> top_k tie/order semantics). Bitmask + ctz walk.
// ---------------------------------------------------------------------------
__global__ __launch_bounds__(256) void build_nbrs(
    const int* __restrict__ dst_s, const int* __restrict__ dst_t,
    int* __restrict__ nbr_s, int* __restrict__ deg_s,
    int* __restrict__ nbr_t, int* __restrict__ deg_t)
{
    int g = blockIdx.x * 256 + threadIdx.x;   // grid is exactly 2*NB*NN threads
    const int* dst; int* nbr; int* deg; int node;
    if (g < NB * NN) { node = g;           dst = dst_s; nbr = nbr_s; deg = deg_s; }
    else             { node = g - NB * NN; dst = dst_t; nbr = nbr_t; deg = deg_t; }

    unsigned long long mlo = 0ull, mhi = 0ull;
    #pragma unroll
    for (int k = 0; k < DEG; ++k) {
        int d = dst[node * DEG + k] & (NN - 1);
        if (d < 64) mlo |= 1ull << d;
        else        mhi |= 1ull << (d - 64);
    }
    int cnt = 0;
    while (mlo) { int t = __builtin_ctzll(mlo); mlo &= (mlo - 1ull); nbr[node * DEG + cnt] = t;      ++cnt; }
    while (mhi) { int t = __builtin_ctzll(mhi); mhi &= (mhi - 1ull); nbr[node * DEG + cnt] = 64 + t; ++cnt; }
    deg[node] = cnt;
    for (int p = cnt; p < DEG; ++p) nbr[node * DEG + p] = 0;  // masked slots, never used
}

// ---------------------------------------------------------------------------
// Kernel 2: sim[b,i,j] = dot(x_s[b,i,:], x_t[b,j,:]).  Block = (b,i), thread=j.
// ---------------------------------------------------------------------------
__global__ __launch_bounds__(128) void sim_kernel(
    const float* __restrict__ xs, const float* __restrict__ xt,
    float* __restrict__ sim)
{
    int bi = blockIdx.x;
    int b = bi >> 7, i = bi & 127, j = threadIdx.x;
    const float4* a  = (const float4*)(xs + (size_t)(b * NN + i) * NC);
    const float4* bt = (const float4*)(xt + (size_t)(b * NN + j) * NC);
    float acc = 0.f;
    #pragma unroll
    for (int k = 0; k < NC / 4; ++k) {
        float4 av = a[k], bv = bt[k];
        acc += av.x * bv.x + av.y * bv.y + av.z * bv.z + av.w * bv.w;
    }
    sim[(size_t)(b * NN + i) * NN + j] = acc;
}

// ---------------------------------------------------------------------------
// Kernel 3: per (b,i) block, thread j.
// Rank-factored Sinkhorn: S[p][q] == T[p][q]*a[p]*b[q] exactly throughout,
// where T = exp(S_hat - rowmax) (masked -> 0), a folds softmax-denominator
// and /tau, b starts at 1 (masked -> 0). Each col/row normalization is a
// scalar update of b[q]/a[p]: 10 divisions instead of 100.
//   col: b[q] <- b[q] / (b[q]*sum_p(T[p][q]*a[p]) + 1e-8)
//   row: a[p] <- a[p] / (a[p]*sum_q(T[p][q]*b[q]) + 1e-8)
// argmax_q S[p][q] == argmax_q T[p][q]*b[q]  (a[p] > 0 constant per row).
// Masked entries stay EXACT zeros (predicated updates), matching reference.
// ---------------------------------------------------------------------------
__global__ __launch_bounds__(128) void main_kernel(
    const float* __restrict__ sim,
    const int* __restrict__ nbr_s, const int* __restrict__ deg_s,
    const int* __restrict__ nbr_t, const int* __restrict__ deg_t,
    float* __restrict__ out)
{
    __shared__ float srow[DEG][NN];   // sim rows of i's neighbors
    __shared__ float smax[2], ssum[2];

    int bi = blockIdx.x;
    int b = bi >> 7, i = bi & 127, j = threadIdx.x;
    int gs = b * NN + i, gt = b * NN + j;

    int dsi = deg_s[gs];              // uniform across block
    float simv = sim[(size_t)gs * NN + j];   // prefetch for epilogue

    // stage neighbor sim rows (coalesced, 128 floats per row)
    #pragma unroll
    for (int p = 0; p < DEG; ++p) {
        if (p < dsi) srow[p][j] = sim[(size_t)(b * NN + nbr_s[gs * DEG + p]) * NN + j];
    }
    __syncthreads();

    int dtj = deg_t[gt];
    int ntq[DEG];
    #pragma unroll
    for (int q = 0; q < DEG; ++q) ntq[q] = nbr_t[gt * DEG + q];

    // Build T = exp(S_hat - rowmax), a = (1/rowsum)/tau, b = valid?1:0
    float T[DEG][DEG];
    float a[DEG], bv[DEG];
    #pragma unroll
    for (int q = 0; q < DEG; ++q) bv[q] = (q < dtj) ? 1.0f : 0.0f;

    #pragma unroll
    for (int p = 0; p < DEG; ++p) {
        bool pv = (p < dsi);
        float v[DEG];
        float mx = -INFINITY;
        #pragma unroll
        for (int q = 0; q < DEG; ++q) {
            bool ok = pv && (q < dtj);
            v[q] = ok ? srow[p][ntq[q]] : 0.0f;
            if (ok) mx = fmaxf(mx, v[q]);
        }
        float sum = 0.f;
        #pragma unroll
        for (int q = 0; q < DEG; ++q) {
            bool ok = pv && (q < dtj);
            float e = ok ? __expf(v[q] - mx) : 0.0f;
            T[p][q] = e;
            sum += e;
        }
        a[p] = pv ? (1.0f / sum) / 0.1f : 0.0f;
    }

    // 5 Sinkhorn iterations on the scale vectors only
    #pragma unroll 1
    for (int it = 0; it < NUM_STEPS; ++it) {
        #pragma unroll
        for (int q = 0; q < DEG; ++q) {
            float c = T[0][q] * a[0];
            #pragma unroll
            for (int p = 1; p < DEG; ++p) c = fmaf(T[p][q], a[p], c);
            float bq = bv[q];
            bv[q] = (q < dtj) ? bq / (bq * c + 1e-8f) : 0.0f;
        }
        #pragma unroll
        for (int p = 0; p < DEG; ++p) {
            float r = T[p][0] * bv[0];
            #pragma unroll
            for (int q = 1; q < DEG; ++q) r = fmaf(T[p][q], bv[q], r);
            float ap = a[p];
            a[p] = (p < dsi) ? ap / (ap * r + 1e-8f) : 0.0f;
        }
    }

    // argmax per row over T[p][q]*b[q] (first max), cost gather from LDS
    float cost = 0.f;
    #pragma unroll
    for (int p = 0; p < DEG; ++p) {
        if (p < dsi) {                       // uniform branch
            float best = T[p][0] * bv[0];
            int   bc   = ntq[0];
            #pragma unroll
            for (int q = 1; q < DEG; ++q) {
                float vq = T[p][q] * bv[q];
                if (vq > best) { best = vq; bc = ntq[q]; }
            }
            cost += srow[p][bc];
        }
    }

    float M = (float)((dsi > dtj) ? dsi : dtj);
    float v = simv + cost / (1.0f + M);

    // block softmax over j (128 threads = 2 waves)
    float wm = v;
    #pragma unroll
    for (int off = 32; off; off >>= 1) wm = fmaxf(wm, __shfl_xor(wm, off));
    int wid = threadIdx.x >> 6;
    if ((threadIdx.x & 63) == 0) smax[wid] = wm;
    __syncthreads();
    float bm = fmaxf(smax[0], smax[1]);
    float e = __expf(v - bm);
    float wsum = e;
    #pragma unroll
    for (int off = 32; off; off >>= 1) wsum += __shfl_xor(wsum, off);
    if ((threadIdx.x & 63) == 0) ssum[wid] = wsum;
    __syncthreads();
    float bs = ssum[0] + ssum[1];

    out[(size_t)gs * NN + j] = e / bs;
}

// ---------------------------------------------------------------------------
extern "C" void kernel_launch(void* const* d_in, const int* in_sizes, int n_in,
                              void* d_out, int out_size, void* d_ws, size_t ws_size,
                              hipStream_t stream) {
    (void)in_sizes; (void)n_in; (void)out_size; (void)ws_size;
    const float* x_s  = (const float*)d_in[0];
    const int*   ei_s = (const int*)  d_in[1];
    const float* x_t  = (const float*)d_in[3];
    const int*   ei_t = (const int*)  d_in[4];
    float* out = (float*)d_out;

    char* ws = (char*)d_ws;
    float* sim   = (float*)ws;                          // 8*128*128*4 = 524288 B
    int*   nbr_s = (int*)(ws + 524288);                 // 1024*10*4   = 40960 B
    int*   deg_s = (int*)(ws + 524288 + 40960);         // 1024*4      = 4096 B
    int*   nbr_t = (int*)(ws + 524288 + 45056);         // 40960 B
    int*   deg_t = (int*)(ws + 524288 + 86016);         // 4096 B

    const int* dst_s = ei_s + NB * NN * DEG;            // second row of edge_index
    const int* dst_t = ei_t + NB * NN * DEG;

    hipLaunchKernelGGL(build_nbrs, dim3(8), dim3(256), 0, stream,
                       dst_s, dst_t, nbr_s, deg_s, nbr_t, deg_t);
    hipLaunchKernelGGL(sim_kernel, dim3(NB * NN), dim3(NN), 0, stream,
                       x_s, x_t, sim);
    hipLaunchKernelGGL(main_kernel, dim3(NB * NN), dim3(NN), 0, stream,
                       sim, nbr_s, deg_s, nbr_t, deg_t, out);
}

// Round 3
// 29.325 us; speedup vs baseline: 2.5716x; 1.2588x over previous
//
#include <hip/hip_runtime.h>
#include <stdint.h>
#include <math.h>

#define NB 8
#define NN 128
#define NC 64
#define DEG 10
#define NUM_STEPS 5

// ---------------------------------------------------------------------------
// Kernel 1: neighbor-list extraction (distinct neighbors sorted ascending,
// matching to_dense_adj -> top_k tie/order semantics). Bitmask + ctz walk.
// ---------------------------------------------------------------------------
__global__ __launch_bounds__(256) void build_nbrs(
    const int* __restrict__ dst_s, const int* __restrict__ dst_t,
    int* __restrict__ nbr_s, int* __restrict__ deg_s,
    int* __restrict__ nbr_t, int* __restrict__ deg_t)
{
    int g = blockIdx.x * 256 + threadIdx.x;   // grid is exactly 2*NB*NN threads
    const int* dst; int* nbr; int* deg; int node;
    if (g < NB * NN) { node = g;           dst = dst_s; nbr = nbr_s; deg = deg_s; }
    else             { node = g - NB * NN; dst = dst_t; nbr = nbr_t; deg = deg_t; }

    unsigned long long mlo = 0ull, mhi = 0ull;
    #pragma unroll
    for (int k = 0; k < DEG; ++k) {
        int d = dst[node * DEG + k] & (NN - 1);
        if (d < 64) mlo |= 1ull << d;
        else        mhi |= 1ull << (d - 64);
    }
    int cnt = 0;
    while (mlo) { int t = __builtin_ctzll(mlo); mlo &= (mlo - 1ull); nbr[node * DEG + cnt] = t;      ++cnt; }
    while (mhi) { int t = __builtin_ctzll(mhi); mhi &= (mhi - 1ull); nbr[node * DEG + cnt] = 64 + t; ++cnt; }
    deg[node] = cnt;
    for (int p = cnt; p < DEG; ++p) nbr[node * DEG + p] = 0;  // masked slots, never used
}

// ---------------------------------------------------------------------------
// Kernel 2: sim[b,i,j] = dot(x_s[b,i,:], x_t[b,j,:]).  Block = (b,i), thread=j.
// ---------------------------------------------------------------------------
__global__ __launch_bounds__(128) void sim_kernel(
    const float* __restrict__ xs, const float* __restrict__ xt,
    float* __restrict__ sim)
{
    int bi = blockIdx.x;
    int b = bi >> 7, i = bi & 127, j = threadIdx.x;
    const float4* a  = (const float4*)(xs + (size_t)(b * NN + i) * NC);
    const float4* bt = (const float4*)(xt + (size_t)(b * NN + j) * NC);
    float acc = 0.f;
    #pragma unroll
    for (int k = 0; k < NC / 4; ++k) {
        float4 av = a[k], bv = bt[k];
        acc += av.x * bv.x + av.y * bv.y + av.z * bv.z + av.w * bv.w;
    }
    sim[(size_t)(b * NN + i) * NN + j] = acc;
}

// ---------------------------------------------------------------------------
// Kernel 3: per (b,i) block, thread j.
// Rank-factored Sinkhorn: S[p][q] == T[p][q]*a[p]*b[q] throughout, with
// T = exp(S_hat) staged once per block (exp is monotone + row-softmax
// normalizes, so the max-subtraction is unnecessary; |sim| <~ 45 keeps
// every product in f32 range). Scalar normalizations via v_rcp_f32:
//   col: b[q] <- b[q] * rcp(fma(b[q], sum_p T[p][q]*a[p], 1e-8))
//   row: a[p] <- a[p] * rcp(fma(a[p], sum_q T[p][q]*b[q], 1e-8))
// argmax_q S[p][q] == argmax_q T[p][q]*b[q]  (a[p] > 0 constant per row).
// Masked entries stay EXACT zeros (predicated updates), matching reference.
// ---------------------------------------------------------------------------
__global__ __launch_bounds__(128, 2) void main_kernel(
    const float* __restrict__ sim,
    const int* __restrict__ nbr_s, const int* __restrict__ deg_s,
    const int* __restrict__ nbr_t, const int* __restrict__ deg_t,
    float* __restrict__ out)
{
    __shared__ float srow[DEG][NN];   // raw sim rows of i's neighbors (cost gather)
    __shared__ float erow[DEG][NN];   // exp(sim) rows (T gather)
    __shared__ float smax[2], ssum[2];

    int bi = blockIdx.x;
    int b = bi >> 7, i = bi & 127, j = threadIdx.x;
    int gs = b * NN + i, gt = b * NN + j;

    int dsi = deg_s[gs];              // uniform across block
    float simv = sim[(size_t)gs * NN + j];   // prefetch for epilogue

    // stage neighbor sim rows + their exp (coalesced, 128 floats per row)
    #pragma unroll
    for (int p = 0; p < DEG; ++p) {
        if (p < dsi) {
            float s = sim[(size_t)(b * NN + nbr_s[gs * DEG + p]) * NN + j];
            srow[p][j] = s;
            erow[p][j] = __expf(s);
        }
    }
    __syncthreads();

    int dtj = deg_t[gt];
    int ntq[DEG];
    #pragma unroll
    for (int q = 0; q < DEG; ++q) ntq[q] = nbr_t[gt * DEG + q];

    // Gather T = exp(S_hat); a = (1/rowsum)/tau via rcp; b = valid?1:0
    float T[DEG][DEG];
    float a[DEG], bv[DEG];
    #pragma unroll
    for (int q = 0; q < DEG; ++q) bv[q] = (q < dtj) ? 1.0f : 0.0f;

    #pragma unroll
    for (int p = 0; p < DEG; ++p) {
        bool pv = (p < dsi);
        float sum = 0.f;
        #pragma unroll
        for (int q = 0; q < DEG; ++q) {
            bool ok = pv && (q < dtj);
            float e = ok ? erow[p][ntq[q]] : 0.0f;
            T[p][q] = e;
            sum += e;
        }
        a[p] = pv ? __builtin_amdgcn_rcpf(sum) * 10.0f : 0.0f;
    }

    // 5 Sinkhorn iterations on the scale vectors only
    #pragma unroll 1
    for (int it = 0; it < NUM_STEPS; ++it) {
        #pragma unroll
        for (int q = 0; q < DEG; ++q) {
            float c = T[0][q] * a[0];
            #pragma unroll
            for (int p = 1; p < DEG; ++p) c = fmaf(T[p][q], a[p], c);
            float bq = bv[q];
            bv[q] = (q < dtj) ? bq * __builtin_amdgcn_rcpf(fmaf(bq, c, 1e-8f)) : 0.0f;
        }
        #pragma unroll
        for (int p = 0; p < DEG; ++p) {
            float r = T[p][0] * bv[0];
            #pragma unroll
            for (int q = 1; q < DEG; ++q) r = fmaf(T[p][q], bv[q], r);
            float ap = a[p];
            a[p] = (p < dsi) ? ap * __builtin_amdgcn_rcpf(fmaf(ap, r, 1e-8f)) : 0.0f;
        }
    }

    // argmax per row over T[p][q]*b[q] (first max), cost gather from LDS
    float cost = 0.f;
    #pragma unroll
    for (int p = 0; p < DEG; ++p) {
        if (p < dsi) {                       // uniform branch
            float best = T[p][0] * bv[0];
            int   bc   = ntq[0];
            #pragma unroll
            for (int q = 1; q < DEG; ++q) {
                float vq = T[p][q] * bv[q];
                if (vq > best) { best = vq; bc = ntq[q]; }
            }
            cost += srow[p][bc];
        }
    }

    float M = (float)((dsi > dtj) ? dsi : dtj);
    float v = simv + cost / (1.0f + M);

    // block softmax over j (128 threads = 2 waves)
    float wm = v;
    #pragma unroll
    for (int off = 32; off; off >>= 1) wm = fmaxf(wm, __shfl_xor(wm, off));
    int wid = threadIdx.x >> 6;
    if ((threadIdx.x & 63) == 0) smax[wid] = wm;
    __syncthreads();
    float bm = fmaxf(smax[0], smax[1]);
    float e = __expf(v - bm);
    float wsum = e;
    #pragma unroll
    for (int off = 32; off; off >>= 1) wsum += __shfl_xor(wsum, off);
    if ((threadIdx.x & 63) == 0) ssum[wid] = wsum;
    __syncthreads();
    float bs = ssum[0] + ssum[1];

    out[(size_t)gs * NN + j] = e / bs;
}

// ---------------------------------------------------------------------------
extern "C" void kernel_launch(void* const* d_in, const int* in_sizes, int n_in,
                              void* d_out, int out_size, void* d_ws, size_t ws_size,
                              hipStream_t stream) {
    (void)in_sizes; (void)n_in; (void)out_size; (void)ws_size;
    const float* x_s  = (const float*)d_in[0];
    const int*   ei_s = (const int*)  d_in[1];
    const float* x_t  = (const float*)d_in[3];
    const int*   ei_t = (const int*)  d_in[4];
    float* out = (float*)d_out;

    char* ws = (char*)d_ws;
    float* sim   = (float*)ws;                          // 8*128*128*4 = 524288 B
    int*   nbr_s = (int*)(ws + 524288);                 // 1024*10*4   = 40960 B
    int*   deg_s = (int*)(ws + 524288 + 40960);         // 1024*4      = 4096 B
    int*   nbr_t = (int*)(ws + 524288 + 45056);         // 40960 B
    int*   deg_t = (int*)(ws + 524288 + 86016);         // 4096 B

    const int* dst_s = ei_s + NB * NN * DEG;            // second row of edge_index
    const int* dst_t = ei_t + NB * NN * DEG;

    hipLaunchKernelGGL(build_nbrs, dim3(8), dim3(256), 0, stream,
                       dst_s, dst_t, nbr_s, deg_s, nbr_t, deg_t);
    hipLaunchKernelGGL(sim_kernel, dim3(NB * NN), dim3(NN), 0, stream,
                       x_s, x_t, sim);
    hipLaunchKernelGGL(main_kernel, dim3(NB * NN), dim3(NN), 0, stream,
                       sim, nbr_s, deg_s, nbr_t, deg_t, out);
}